// Round 1
// 25183.875 us; speedup vs baseline: 1.0936x; 1.0936x over previous
//
#include <hip/hip_runtime.h>
#include <stdint.h>

// ---------------------------------------------------------------------------
// Persistent-grid GRU, fence-free cross-WG pipeline.
//  - 4 batch-groups x 16 rows, 64 WGs/group (256 WGs ~ 1/CU).
//  - Weights live in REGISTERS (step-invariant bf16 hi/lo MFMA B-fragments).
//  - Recurrent state transported as packed (bf16_hi<<16)|bf16_lo u32 planes
//    via agent-scope relaxed atomics (coherence-point ops, no L2 flushes).
//  - R1 change: per-WG FLAG ARRAYS replace the shared atomic counters.
//    64 same-address atomicAdd RMWs serialized at the LLC each phase
//    (~8k cy) -> 64 independent fire-and-forget word stores + lane-parallel
//    poll (__all over 64 flags). `out` HBM store moved off the release path.
// ---------------------------------------------------------------------------

#define T_STEPS 2048
#define B_SZ    64
#define D_SZ    256
#define H_SZ    512
#define NGROUP  4
#define NWG     64
#define MB      16
#define CPW     6     // K-chunks (of 32) per wave; 4 waves * 6 = 24 = K 768

typedef __attribute__((ext_vector_type(8))) short  short8;
typedef __attribute__((ext_vector_type(4))) float  f32x4;

__device__ __forceinline__ unsigned short f2bf(float v) {
  uint32_t u = __float_as_uint(v);
  return (unsigned short)((u + 0x7fffu + ((u >> 16) & 1u)) >> 16);   // RTNE
}
__device__ __forceinline__ float bf2f(unsigned short h) {
  return __uint_as_float(((uint32_t)h) << 16);
}
__device__ __forceinline__ void splitf(float v, short& hi, short& lo) {
  unsigned short h = f2bf(v);
  hi = (short)h;
  lo = (short)f2bf(v - bf2f(h));
}
__device__ __forceinline__ uint32_t packf(float v) {
  unsigned short h = f2bf(v);
  unsigned short l = f2bf(v - bf2f(h));
  return ((uint32_t)h << 16) | (uint32_t)l;
}
__device__ __forceinline__ float unpackf(uint32_t p) {
  return __uint_as_float(p & 0xffff0000u) + __uint_as_float(p << 16);
}

__device__ __forceinline__ uint32_t aload32(const uint32_t* p) {
  return __hip_atomic_load(p, __ATOMIC_RELAXED, __HIP_MEMORY_SCOPE_AGENT);
}
__device__ __forceinline__ unsigned long long aload64(const uint32_t* p) {
  return __hip_atomic_load((const unsigned long long*)p, __ATOMIC_RELAXED,
                           __HIP_MEMORY_SCOPE_AGENT);
}
__device__ __forceinline__ void astore32(uint32_t* p, uint32_t v) {
  __hip_atomic_store(p, v, __ATOMIC_RELAXED, __HIP_MEMORY_SCOPE_AGENT);
}

// Lane-parallel flag poll: lane i watches flags[i]; wave-uniform exit.
__device__ __forceinline__ void poll_flags(const uint32_t* fl, uint32_t tgt,
                                           int lane, int& cap) {
  int guard = 0;
  for (;;) {
    uint32_t v = aload32(fl + lane);
    if (__all((int)(v >= tgt))) break;
    if (++guard > cap) { cap = 256; break; }   // degrade, never deadlock
    __builtin_amdgcn_s_sleep(1);
  }
}

__global__ void __launch_bounds__(256, 1)
gru_persistent(const float* __restrict__ x, const float* __restrict__ h0,
               const float* __restrict__ Wz, const float* __restrict__ bz,
               const float* __restrict__ Wr, const float* __restrict__ br,
               const float* __restrict__ Wh, const float* __restrict__ bh,
               float* __restrict__ out,
               uint32_t* zr_flg, uint32_t* h_flg,
               uint32_t* h_pk, uint32_t* rh_pk, uint32_t* z_pk)
{
  __shared__ float partT[16 * 64];   // [kslice i][reg r][lane] transposed: conflict-free
  __shared__ float bias1s[16];
  __shared__ float bias2s[8];

  const int tid  = threadIdx.x;
  const int wv   = tid >> 6;
  const int lane = tid & 63;
  const int blk  = blockIdx.x;
  const int g    = blk >> 6;           // contiguous grouping: dispatch-order safe
  const int wid  = blk & 63;
  const int m0   = g * MB;
  const bool isZ = (wid < 32);
  const int c1   = (wid & 31) * 16;    // phase-1 column base (z or r gate)
  const int c2   = wid * 8;            // phase-2 column base (h gate)
  const float* W1 = isZ ? Wz : Wr;

  const int n     = lane & 15;         // MFMA fragment col / A-row-in-tile
  const int kq    = lane >> 4;         // k-quad
  const int bfrag = m0 + n;            // batch row this lane's A fragment holds
  const int m2    = kq * 4 + wv;       // C-layout row for this thread
  const int n2    = n;                 // C-layout col
  const int b2    = m0 + m2;

  uint32_t* my_zr = zr_flg + g * 64;   // per-WG flag words, 256 B per group
  uint32_t* my_h  = h_flg  + g * 64;

  // ---- weights -> registers (B fragments, bf16 hi/lo; step-invariant) ----
  short8 w1h[CPW], w1l[CPW], w2h[CPW], w2l[CPW];
  #pragma unroll
  for (int i = 0; i < CPW; ++i) {
    const int ch = wv * CPW + i;
    #pragma unroll
    for (int j = 0; j < 8; ++j) {
      const int k = ch * 32 + kq * 8 + j;
      short hi, lo;
      splitf(W1[(size_t)k * H_SZ + c1 + n], hi, lo);
      w1h[i][j] = hi; w1l[i][j] = lo;
      float v = (n < 8) ? Wh[(size_t)k * H_SZ + c2 + n] : 0.f;
      splitf(v, hi, lo);
      w2h[i][j] = hi; w2l[i][j] = lo;
    }
  }
  if (tid < 16)      bias1s[tid] = isZ ? bz[c1 + tid] : br[c1 + tid];
  else if (tid < 24) bias2s[tid - 16] = bh[c2 + (tid - 16)];
  __syncthreads();

  // own recurrent column kept as exact f32 register chain
  float hreg = (n2 < 8) ? h0[(size_t)b2 * H_SZ + c2 + n2] : 0.f;

  int cap = 1 << 20;

  #pragma unroll 1
  for (int t = 0; t < T_STEPS; ++t) {
    short8 ah[CPW], al[CPW];

    // ---- x fragments (chunks 0..7): independent of h, issue before poll ----
    #pragma unroll
    for (int i = 0; i < CPW; ++i) {
      const int ch = wv * CPW + i;
      if (ch < 8) {
        const float* xp = x + ((size_t)t * B_SZ + bfrag) * D_SZ + ch * 32 + kq * 8;
        float4 f0 = *(const float4*)xp;
        float4 f1 = *(const float4*)(xp + 4);
        float f[8] = {f0.x, f0.y, f0.z, f0.w, f1.x, f1.y, f1.z, f1.w};
        #pragma unroll
        for (int j = 0; j < 8; ++j) { short hi, lo; splitf(f[j], hi, lo); ah[i][j] = hi; al[i][j] = lo; }
      }
    }

    // ---- wait for h_{t-1}: all 64 per-WG flags >= t (lane-parallel) ----
    if (t > 0) poll_flags(my_h, (uint32_t)t, lane, cap);

    // early per-thread load: r-gate needs own h_{t-1}[b2, c1+n2]
    uint32_t hpu = 0; float hp0 = 0.f;
    if (!isZ) {
      if (t > 0) hpu = aload32(h_pk + (size_t)b2 * H_SZ + c1 + n2);
      else       hp0 = h0[(size_t)b2 * H_SZ + c1 + n2];
    }

    // ---- h fragments (chunks 8..23) straight into registers ----
    #pragma unroll
    for (int i = 0; i < CPW; ++i) {
      const int ch = wv * CPW + i;
      if (ch >= 8) {
        const int kh = ch * 32 - 256 + kq * 8;
        if (t > 0) {
          const uint32_t* hp = h_pk + (size_t)bfrag * H_SZ + kh;
          unsigned long long q0 = aload64(hp),     q1 = aload64(hp + 2);
          unsigned long long q2 = aload64(hp + 4), q3 = aload64(hp + 6);
          uint32_t u[8] = {(uint32_t)q0, (uint32_t)(q0 >> 32), (uint32_t)q1, (uint32_t)(q1 >> 32),
                           (uint32_t)q2, (uint32_t)(q2 >> 32), (uint32_t)q3, (uint32_t)(q3 >> 32)};
          #pragma unroll
          for (int j = 0; j < 8; ++j) { ah[i][j] = (short)(u[j] >> 16); al[i][j] = (short)(u[j] & 0xffffu); }
        } else {
          const float* hp = h0 + (size_t)bfrag * H_SZ + kh;
          float4 f0 = *(const float4*)hp;
          float4 f1 = *(const float4*)(hp + 4);
          float f[8] = {f0.x, f0.y, f0.z, f0.w, f1.x, f1.y, f1.z, f1.w};
          #pragma unroll
          for (int j = 0; j < 8; ++j) { short hi, lo; splitf(f[j], hi, lo); ah[i][j] = hi; al[i][j] = lo; }
        }
      }
    }

    // ---- phase-1 MFMA: [16,768] @ [768,16], 3-term hi/lo split ----
    {
      f32x4 acc = {0.f, 0.f, 0.f, 0.f};
      #pragma unroll
      for (int i = 0; i < CPW; ++i) {
        acc = __builtin_amdgcn_mfma_f32_16x16x32_bf16(ah[i], w1h[i], acc, 0, 0, 0);
        acc = __builtin_amdgcn_mfma_f32_16x16x32_bf16(al[i], w1h[i], acc, 0, 0, 0);
        acc = __builtin_amdgcn_mfma_f32_16x16x32_bf16(ah[i], w1l[i], acc, 0, 0, 0);
      }
      #pragma unroll
      for (int r = 0; r < 4; ++r) partT[(wv * 4 + r) * 64 + lane] = acc[r];
    }
    __syncthreads();

    // ---- reduce K-slices, activate, publish z / r*h (coherent stores) ----
    {
      float s = partT[(0 + wv) * 64 + lane] + partT[(4 + wv) * 64 + lane]
              + partT[(8 + wv) * 64 + lane] + partT[(12 + wv) * 64 + lane] + bias1s[n2];
      float sg = 1.f / (1.f + __expf(-s));
      if (isZ) {
        astore32(z_pk + (size_t)b2 * H_SZ + c1 + n2, __float_as_uint(sg));
      } else {
        float hp = (t > 0) ? unpackf(hpu) : hp0;
        astore32(rh_pk + (size_t)b2 * H_SZ + c1 + n2, packf(sg * hp));
      }
    }
    asm volatile("s_waitcnt vmcnt(0)" ::: "memory");  // stores complete at coherence point
    __syncthreads();
    if (tid == 0) astore32(my_zr + wid, (uint32_t)(t + 1));   // fire-and-forget release

    // ---- wait for all z / r*h of step t (64 flags >= t+1) ----
    poll_flags(my_zr, (uint32_t)(t + 1), lane, cap);

    uint32_t zu = 0;
    if (n2 < 8) zu = aload32(z_pk + (size_t)b2 * H_SZ + c2 + n2);  // overlap with MFMA

    // ---- rh fragments (chunks 8..23); x chunks still in regs ----
    #pragma unroll
    for (int i = 0; i < CPW; ++i) {
      const int ch = wv * CPW + i;
      if (ch >= 8) {
        const int kh = ch * 32 - 256 + kq * 8;
        const uint32_t* rp = rh_pk + (size_t)bfrag * H_SZ + kh;
        unsigned long long q0 = aload64(rp),     q1 = aload64(rp + 2);
        unsigned long long q2 = aload64(rp + 4), q3 = aload64(rp + 6);
        uint32_t u[8] = {(uint32_t)q0, (uint32_t)(q0 >> 32), (uint32_t)q1, (uint32_t)(q1 >> 32),
                         (uint32_t)q2, (uint32_t)(q2 >> 32), (uint32_t)q3, (uint32_t)(q3 >> 32)};
        #pragma unroll
        for (int j = 0; j < 8; ++j) { ah[i][j] = (short)(u[j] >> 16); al[i][j] = (short)(u[j] & 0xffffu); }
      }
    }

    // ---- phase-2 MFMA: h-candidate slice (8 live cols, 8 zero-padded) ----
    {
      f32x4 acc = {0.f, 0.f, 0.f, 0.f};
      #pragma unroll
      for (int i = 0; i < CPW; ++i) {
        acc = __builtin_amdgcn_mfma_f32_16x16x32_bf16(ah[i], w2h[i], acc, 0, 0, 0);
        acc = __builtin_amdgcn_mfma_f32_16x16x32_bf16(al[i], w2h[i], acc, 0, 0, 0);
        acc = __builtin_amdgcn_mfma_f32_16x16x32_bf16(ah[i], w2l[i], acc, 0, 0, 0);
      }
      #pragma unroll
      for (int r = 0; r < 4; ++r) partT[(wv * 4 + r) * 64 + lane] = acc[r];
    }
    __syncthreads();

    // ---- reduce, tanh, h-update (exact f32 register chain), publish ----
    float hn = 0.f; bool live = (n2 < 8);
    if (live) {
      float s = partT[(0 + wv) * 64 + lane] + partT[(4 + wv) * 64 + lane]
              + partT[(8 + wv) * 64 + lane] + partT[(12 + wv) * 64 + lane] + bias2s[n2];
      float e  = __expf(2.f * s);
      float ht = 1.f - 2.f / (e + 1.f);
      float zf = __uint_as_float(zu);
      hn = (1.f - zf) * hreg + zf * ht;
      hreg = hn;
      astore32(h_pk + (size_t)b2 * H_SZ + c2 + n2, packf(hn));   // recurrent plane first
    }
    asm volatile("s_waitcnt vmcnt(0)" ::: "memory");  // h_pk at coherence point
    __syncthreads();
    if (tid == 0) astore32(my_h + wid, (uint32_t)(t + 1));       // release step t

    // HBM history write AFTER release: off the critical path
    if (live)
      __builtin_nontemporal_store(hn, out + ((size_t)t * B_SZ + b2) * H_SZ + c2 + n2);
  }
}

extern "C" void kernel_launch(void* const* d_in, const int* in_sizes, int n_in,
                              void* d_out, int out_size, void* d_ws, size_t ws_size,
                              hipStream_t stream) {
  const float* x  = (const float*)d_in[0];
  const float* h0 = (const float*)d_in[1];
  const float* Wz = (const float*)d_in[2];
  const float* bz = (const float*)d_in[3];
  const float* Wr = (const float*)d_in[4];
  const float* br = (const float*)d_in[5];
  const float* Wh = (const float*)d_in[6];
  const float* bh = (const float*)d_in[7];
  float* out = (float*)d_out;

  char* ws = (char*)d_ws;
  uint32_t* zr_flg = (uint32_t*)(ws + 0);        // per-WG release flags [4][64]
  uint32_t* h_flg  = (uint32_t*)(ws + 16384);    // per-WG release flags [4][64]
  uint32_t* h_pk   = (uint32_t*)(ws + 32768);    // [64][512] packed bf16 hi|lo
  uint32_t* rh_pk  = (uint32_t*)(ws + 163840);
  uint32_t* z_pk   = (uint32_t*)(ws + 294912);   // [64][512] f32 bits

  // zero only the flags; data planes are written before they are read
  hipMemsetAsync(d_ws, 0, 32768, stream);
  gru_persistent<<<dim3(NGROUP * NWG), dim3(256), 0, stream>>>(
      x, h0, Wz, bz, Wr, br, Wh, bh, out,
      zr_flg, h_flg, h_pk, rh_pk, z_pk);
}